// Round 15
// baseline (77.507 us; speedup 1.0000x reference)
//
#include <hip/hip_runtime.h>
#include <hip/hip_cooperative_groups.h>
#include <math.h>

namespace cg = cooperative_groups;

// Problem constants (fixed by the reference)
constexpr int B_    = 8;
constexpr int CIN_  = 128;
constexpr int COUT_ = 256;
constexpr int L_    = 784;
constexpr int N_    = B_ * L_;       // 6272
constexpr int NCB_  = 64;
constexpr int K_    = 16;
constexpr int SUB_  = 18;            // 2 channels x 9 taps
constexpr int NGRP  = N_ / 4;        // 1568 groups of 4 positions
constexpr int NBLK  = 512;           // == guaranteed co-resident capacity

// ws layout (byte offsets). idx layout [cb][n] (cb-major).
constexpr size_t WS_IDX  = 0;                  // 64*6272 uchar = 401408 B
constexpr size_t WS_LUT8 = 0x100000;           // 262144 uchar = 256 KB
constexpr size_t WS_BF2  = 0x180000;           // 256 f32 (bias + folded consts)

// ===========================================================================
// Cooperative single-dispatch kernel. Grid = 512 (= 2 blocks/CU floor from
// __launch_bounds__(256,2), so the cooperative-launch capacity check passes).
// Phase A: every block: pack slice (128 int4, threads 0..127) + argmin for
// (cb = bx&63, b = bx>>6); block 0 additionally preps bias. == R9 arithmetic.
// grid.sync()
// Phase B: groups g = bx, bx+512, ... (R13 dwordx4 gather, verbatim).
// ===========================================================================
__global__ __launch_bounds__(256, 2) void amm_all(
    const int* __restrict__ x_q, const int* __restrict__ x_z,
    const int* __restrict__ c_q, const float* __restrict__ c_s,
    const int* __restrict__ c_z, const float* __restrict__ x_s,
    const int* __restrict__ lut_q, const float* __restrict__ lut_s,
    const int* __restrict__ lut_z,
    const int* __restrict__ bias_q, const float* __restrict__ bias_s,
    const int* __restrict__ bias_z,
    const float* __restrict__ out_s, const int* __restrict__ out_z,
    unsigned char* __restrict__ idx8, unsigned char* __restrict__ lut8,
    float* __restrict__ biasf2, int* __restrict__ out)
{
    const int bx  = blockIdx.x;
    const int tid = threadIdx.x;

    __shared__ float sx[2][900];          // 30x30 zero-padded, 7.2 KB
    __shared__ float c_lds[288];          // [s][k] k-major, float(c_q - zc)
    __shared__ float y2_lds[16];
    __shared__ unsigned int sidx[64];     // phase B: [cb] 4 pos bytes
    __shared__ unsigned int res[4][132];  // phase B: [pos][128 words] +pad

    // ---- pack slice: 512 blocks x 128 int4 = 65536 int4 = 262144 dwords ----
    if (tid < 128) {
        const int i = (bx * 128 + tid) * 4;
        const int4 v = *(const int4*)(lut_q + i);
        uchar4 o;
        o.x = (unsigned char)(v.x + 128);
        o.y = (unsigned char)(v.y + 128);
        o.z = (unsigned char)(v.z + 128);
        o.w = (unsigned char)(v.w + 128);
        *(uchar4*)(lut8 + i) = o;
    }
    if (bx == 0) {
        const double ls = (double)lut_s[0];
        const double c0 = (8192.0 + 64.0 * (double)lut_z[0]) * ls;
        biasf2[tid] = (float)((double)(bias_q[tid] - bias_z[0]) *
                              (double)bias_s[0] - c0);
    }

    // ---- argmin for (cb, b) — R9 k1 verbatim ----
    {
        const int cb = bx & 63;
        const int b  = bx >> 6;

        const int zc = c_z[cb];
        for (int i = tid; i < 1800; i += 256) ((float*)sx)[i] = 0.0f;
        for (int i = tid; i < 288; i += 256) {
            const int k = i / SUB_, s = i - k * SUB_;
            c_lds[s * 16 + k] = (float)(c_q[cb * 288 + i] - zc);   // exact int
        }
        __syncthreads();

        const int xz = x_z[0];
        for (int i = tid; i < 2 * 784; i += 256) {
            const int c2 = i >= 784;
            const int r  = i - c2 * 784;
            const int h  = r / 28;
            const int w  = r - h * 28;
            sx[c2][(h + 1) * 30 + (w + 1)] =
                (float)(x_q[(size_t)(b * CIN_ + 2 * cb + c2) * L_ + r] - xz);
        }
        if (tid < 16) {                 // y2 in double, same order as before
            const double csf = (double)c_s[cb];
            const double den = (double)x_s[0] * csf;
            double s2 = 0.0;
            for (int s = 0; s < SUB_; ++s) {
                const double d = (double)c_lds[s * 16 + tid] * csf;
                s2 += d * d;
            }
            y2_lds[tid] = (float)(int)rint(s2 / den);   // < 2^24 exact in f32
        }
        __syncthreads();

        if (tid < 196) {
            float tap[4][SUB_];
            int   posr[4];
            #pragma unroll
            for (int ps = 0; ps < 4; ++ps) {
                const int p  = tid + 196 * ps;
                posr[ps] = p;
                const int oh = p / 28;
                const int ow = p - oh * 28;
                const int base = oh * 30 + ow;
                #pragma unroll
                for (int c2 = 0; c2 < 2; ++c2)
                    #pragma unroll
                    for (int kh = 0; kh < 3; ++kh)
                        #pragma unroll
                        for (int kw = 0; kw < 3; ++kw)
                            tap[ps][c2 * 9 + kh * 3 + kw] =
                                sx[c2][base + kh * 30 + kw];
            }

            float bestd[4] = {3.0e38f, 3.0e38f, 3.0e38f, 3.0e38f};
            int   bestk[4] = {0, 0, 0, 0};

            #pragma unroll
            for (int kc = 0; kc < 4; ++kc) {
                float acc[4][4];
                #pragma unroll
                for (int ps = 0; ps < 4; ++ps)
                    #pragma unroll
                    for (int kk = 0; kk < 4; ++kk) acc[ps][kk] = 0.0f;

                #pragma unroll
                for (int s = 0; s < SUB_; ++s) {
                    const float4 c4 = *(const float4*)&c_lds[s * 16 + kc * 4];
                    #pragma unroll
                    for (int ps = 0; ps < 4; ++ps) {
                        const float xs = tap[ps][s];
                        acc[ps][0] = fmaf(xs, c4.x, acc[ps][0]);
                        acc[ps][1] = fmaf(xs, c4.y, acc[ps][1]);
                        acc[ps][2] = fmaf(xs, c4.z, acc[ps][2]);
                        acc[ps][3] = fmaf(xs, c4.w, acc[ps][3]);
                    }
                }
                #pragma unroll
                for (int kk = 0; kk < 4; ++kk) {
                    const float yk = y2_lds[kc * 4 + kk];
                    #pragma unroll
                    for (int ps = 0; ps < 4; ++ps) {
                        const float d = fmaf(-2.0f, acc[ps][kk], yk);
                        if (d < bestd[ps]) { bestd[ps] = d; bestk[ps] = kc * 4 + kk; }
                    }
                }
            }

            unsigned char* op = idx8 + (size_t)cb * N_ + b * L_;
            #pragma unroll
            for (int ps = 0; ps < 4; ++ps)
                op[posr[ps]] = (unsigned char)bestk[ps];
        }
    }

    // ======================= GRID SYNC =======================
    cg::this_grid().sync();

    // ======================= PHASE B (R13 gather) =======================
    const int lane = tid & 63;
    const int wv   = __builtin_amdgcn_readfirstlane(tid >> 6);  // position
    const int sh   = 8 * wv;
    const int cbq  = lane >> 4;        // row class 0..3
    const int coq  = lane & 15;        // 16B cout-quad within the row

    const float lsf = lut_s[0];
    const float osf = out_s[0];
    const float ozf = (float)out_z[0];
    const int co    = tid;
    const int u     = (co >> 4) * 8 + ((co & 15) >> 2) * 2 + (co & 1);
    const int half  = (co >> 1) & 1;
    const float bf  = biasf2[co];

    for (int g = bx; g < NGRP; g += NBLK) {
        const int nb = g * 4;
        const int b  = nb / L_;
        const int r0 = nb - b * L_;

        __syncthreads();               // protect sidx/res reuse across iters
        if (tid < 64)
            sidx[tid] = *(const unsigned int*)(idx8 + (size_t)tid * N_ + nb);
        __syncthreads();

        unsigned int acc[8] = {0, 0, 0, 0, 0, 0, 0, 0};
        #pragma unroll
        for (int tb = 0; tb < 4; ++tb) {
            uint4 v[4];
            #pragma unroll
            for (int j = 0; j < 4; ++j) {
                const int cb = (tb * 4 + j) * 4 + cbq;
                const unsigned int k = (sidx[cb] >> sh) & 0xffu;
                v[j] = *(const uint4*)(lut8 + ((size_t)((cb << 4) + k) << 8)
                                            + (coq << 4));
            }
            #pragma unroll
            for (int j = 0; j < 4; ++j) {
                const unsigned int d[4] = {v[j].x, v[j].y, v[j].z, v[j].w};
                #pragma unroll
                for (int q = 0; q < 4; ++q) {
                    acc[2 * q]     += d[q] & 0x00FF00FFu;
                    acc[2 * q + 1] += (d[q] >> 8) & 0x00FF00FFu;
                }
            }
        }

        #pragma unroll
        for (int j = 0; j < 8; ++j) {
            acc[j] += __shfl_xor(acc[j], 16, 64);
            acc[j] += __shfl_xor(acc[j], 32, 64);
        }
        if (cbq == 0) {
            #pragma unroll
            for (int j = 0; j < 8; ++j) res[wv][coq * 8 + j] = acc[j];
        }
        __syncthreads();

        int4 ov;
        int* ovp = (int*)&ov;
        #pragma unroll
        for (int p = 0; p < 4; ++p) {
            const unsigned int vv = res[p][u];
            const int sv = (int)((vv >> (16 * half)) & 0xffffu);
            float f = (float)sv * lsf + bf;
            f = fmaxf(f, 0.0f) / osf + ozf;
            f = fminf(fmaxf(f, -128.0f), 127.0f);
            ovp[p] = (int)rintf(f);
        }
        *(int4*)(out + (size_t)(b * COUT_ + co) * L_ + r0) = ov;
    }
}

// ===========================================================================
// Fallback kernels (R13, byte-identical) — used only if the cooperative
// launch is rejected; the error is deterministic so the choice is stable.
// ===========================================================================
__global__ __launch_bounds__(256, 2) void amm_k1(
    const int* __restrict__ x_q, const int* __restrict__ x_z,
    const int* __restrict__ c_q, const float* __restrict__ c_s,
    const int* __restrict__ c_z, const float* __restrict__ x_s,
    const int* __restrict__ lut_q, const float* __restrict__ lut_s,
    const int* __restrict__ lut_z,
    const int* __restrict__ bias_q, const float* __restrict__ bias_s,
    const int* __restrict__ bias_z,
    unsigned char* __restrict__ idx8, unsigned char* __restrict__ lut8,
    float* __restrict__ biasf2)
{
    const int bx  = blockIdx.x;
    const int tid = threadIdx.x;

    if (bx >= 512) {
        const int pb = bx - 512;
        if (pb < 256) {
            const int i = pb * 1024 + tid * 4;
            const int4 v = *(const int4*)(lut_q + i);
            uchar4 o;
            o.x = (unsigned char)(v.x + 128);
            o.y = (unsigned char)(v.y + 128);
            o.z = (unsigned char)(v.z + 128);
            o.w = (unsigned char)(v.w + 128);
            *(uchar4*)(lut8 + i) = o;
        } else {
            const double ls = (double)lut_s[0];
            const double c0 = (8192.0 + 64.0 * (double)lut_z[0]) * ls;
            biasf2[tid] = (float)((double)(bias_q[tid] - bias_z[0]) *
                                  (double)bias_s[0] - c0);
        }
        return;
    }

    const int cb = bx & 63;
    const int b  = bx >> 6;

    __shared__ float sx[2][900];
    __shared__ float c_lds[288];
    __shared__ float y2_lds[16];

    const int zc = c_z[cb];
    for (int i = tid; i < 1800; i += 256) ((float*)sx)[i] = 0.0f;
    for (int i = tid; i < 288; i += 256) {
        const int k = i / SUB_, s = i - k * SUB_;
        c_lds[s * 16 + k] = (float)(c_q[cb * 288 + i] - zc);
    }
    __syncthreads();

    const int xz = x_z[0];
    for (int i = tid; i < 2 * 784; i += 256) {
        const int c2 = i >= 784;
        const int r  = i - c2 * 784;
        const int h  = r / 28;
        const int w  = r - h * 28;
        sx[c2][(h + 1) * 30 + (w + 1)] =
            (float)(x_q[(size_t)(b * CIN_ + 2 * cb + c2) * L_ + r] - xz);
    }
    if (tid < 16) {
        const double csf = (double)c_s[cb];
        const double den = (double)x_s[0] * csf;
        double s2 = 0.0;
        for (int s = 0; s < SUB_; ++s) {
            const double d = (double)c_lds[s * 16 + tid] * csf;
            s2 += d * d;
        }
        y2_lds[tid] = (float)(int)rint(s2 / den);
    }
    __syncthreads();

    if (tid < 196) {
        float tap[4][SUB_];
        int   posr[4];
        #pragma unroll
        for (int ps = 0; ps < 4; ++ps) {
            const int p  = tid + 196 * ps;
            posr[ps] = p;
            const int oh = p / 28;
            const int ow = p - oh * 28;
            const int base = oh * 30 + ow;
            #pragma unroll
            for (int c2 = 0; c2 < 2; ++c2)
                #pragma unroll
                for (int kh = 0; kh < 3; ++kh)
                    #pragma unroll
                    for (int kw = 0; kw < 3; ++kw)
                        tap[ps][c2 * 9 + kh * 3 + kw] =
                            sx[c2][base + kh * 30 + kw];
        }

        float bestd[4] = {3.0e38f, 3.0e38f, 3.0e38f, 3.0e38f};
        int   bestk[4] = {0, 0, 0, 0};

        #pragma unroll
        for (int kc = 0; kc < 4; ++kc) {
            float acc[4][4];
            #pragma unroll
            for (int ps = 0; ps < 4; ++ps)
                #pragma unroll
                for (int kk = 0; kk < 4; ++kk) acc[ps][kk] = 0.0f;

            #pragma unroll
            for (int s = 0; s < SUB_; ++s) {
                const float4 c4 = *(const float4*)&c_lds[s * 16 + kc * 4];
                #pragma unroll
                for (int ps = 0; ps < 4; ++ps) {
                    const float xs = tap[ps][s];
                    acc[ps][0] = fmaf(xs, c4.x, acc[ps][0]);
                    acc[ps][1] = fmaf(xs, c4.y, acc[ps][1]);
                    acc[ps][2] = fmaf(xs, c4.z, acc[ps][2]);
                    acc[ps][3] = fmaf(xs, c4.w, acc[ps][3]);
                }
            }
            #pragma unroll
            for (int kk = 0; kk < 4; ++kk) {
                const float yk = y2_lds[kc * 4 + kk];
                #pragma unroll
                for (int ps = 0; ps < 4; ++ps) {
                    const float d = fmaf(-2.0f, acc[ps][kk], yk);
                    if (d < bestd[ps]) { bestd[ps] = d; bestk[ps] = kc * 4 + kk; }
                }
            }
        }

        unsigned char* op = idx8 + (size_t)cb * N_ + b * L_;
        #pragma unroll
        for (int ps = 0; ps < 4; ++ps)
            op[posr[ps]] = (unsigned char)bestk[ps];
    }
}

__global__ __launch_bounds__(256, 6) void amm_phase2(
    const unsigned char* __restrict__ idx8, const unsigned char* __restrict__ lut8,
    const float* __restrict__ lut_s, const float* __restrict__ biasf2,
    const float* __restrict__ out_s, const int* __restrict__ out_z,
    int* __restrict__ out)
{
    const int tid  = threadIdx.x;
    const int lane = tid & 63;
    const int wv   = __builtin_amdgcn_readfirstlane(tid >> 6);
    const int nb   = blockIdx.x * 4;
    const int b    = nb / L_;
    const int r0   = nb - b * L_;
    const int sh   = 8 * wv;

    __shared__ unsigned int sidx[64];
    __shared__ unsigned int res[4][132];

    if (tid < 64)
        sidx[tid] = *(const unsigned int*)(idx8 + (size_t)tid * N_ + nb);
    __syncthreads();

    const int cbq = lane >> 4;
    const int coq = lane & 15;

    unsigned int acc[8] = {0, 0, 0, 0, 0, 0, 0, 0};
    #pragma unroll
    for (int tb = 0; tb < 4; ++tb) {
        uint4 v[4];
        #pragma unroll
        for (int j = 0; j < 4; ++j) {
            const int cb = (tb * 4 + j) * 4 + cbq;
            const unsigned int k = (sidx[cb] >> sh) & 0xffu;
            v[j] = *(const uint4*)(lut8 + ((size_t)((cb << 4) + k) << 8)
                                        + (coq << 4));
        }
        #pragma unroll
        for (int j = 0; j < 4; ++j) {
            const unsigned int d[4] = {v[j].x, v[j].y, v[j].z, v[j].w};
            #pragma unroll
            for (int q = 0; q < 4; ++q) {
                acc[2 * q]     += d[q] & 0x00FF00FFu;
                acc[2 * q + 1] += (d[q] >> 8) & 0x00FF00FFu;
            }
        }
    }

    #pragma unroll
    for (int j = 0; j < 8; ++j) {
        acc[j] += __shfl_xor(acc[j], 16, 64);
        acc[j] += __shfl_xor(acc[j], 32, 64);
    }
    if (cbq == 0) {
        #pragma unroll
        for (int j = 0; j < 8; ++j) res[wv][coq * 8 + j] = acc[j];
    }
    __syncthreads();

    const float lsf = lut_s[0];
    const float osf = out_s[0];
    const float ozf = (float)out_z[0];

    const int co   = tid;
    const int u    = (co >> 4) * 8 + ((co & 15) >> 2) * 2 + (co & 1);
    const int half = (co >> 1) & 1;
    const float bf = biasf2[co];

    int4 ov;
    int* ovp = (int*)&ov;
    #pragma unroll
    for (int p = 0; p < 4; ++p) {
        const unsigned int vv = res[p][u];
        const int sv = (int)((vv >> (16 * half)) & 0xffffu);
        float f = (float)sv * lsf + bf;
        f = fmaxf(f, 0.0f) / osf + ozf;
        f = fminf(fmaxf(f, -128.0f), 127.0f);
        ovp[p] = (int)rintf(f);
    }
    *(int4*)(out + (size_t)(b * COUT_ + co) * L_ + r0) = ov;
}

extern "C" void kernel_launch(void* const* d_in, const int* in_sizes, int n_in,
                              void* d_out, int out_size, void* d_ws, size_t ws_size,
                              hipStream_t stream)
{
    const int*   x_q    = (const int*)  d_in[0];
    const float* x_s    = (const float*)d_in[1];
    const int*   x_z    = (const int*)  d_in[2];
    const int*   c_q    = (const int*)  d_in[3];
    const float* c_s    = (const float*)d_in[4];
    const int*   c_z    = (const int*)  d_in[5];
    const int*   lut_q  = (const int*)  d_in[6];
    const float* lut_s  = (const float*)d_in[7];
    const int*   lut_z  = (const int*)  d_in[8];
    const int*   bias_q = (const int*)  d_in[9];
    const float* bias_s = (const float*)d_in[10];
    const int*   bias_z = (const int*)  d_in[11];
    const float* out_s  = (const float*)d_in[12];
    const int*   out_z  = (const int*)  d_in[13];

    char* ws = (char*)d_ws;
    unsigned char* idx8 = (unsigned char*)(ws + WS_IDX);
    unsigned char* lut8 = (unsigned char*)(ws + WS_LUT8);
    float* biasf2 = (float*)(ws + WS_BF2);
    int* outp = (int*)d_out;

    void* params[] = {
        (void*)&x_q, (void*)&x_z, (void*)&c_q, (void*)&c_s, (void*)&c_z,
        (void*)&x_s, (void*)&lut_q, (void*)&lut_s, (void*)&lut_z,
        (void*)&bias_q, (void*)&bias_s, (void*)&bias_z,
        (void*)&out_s, (void*)&out_z,
        (void*)&idx8, (void*)&lut8, (void*)&biasf2, (void*)&outp,
    };
    const hipError_t e = hipLaunchCooperativeKernel(
        (const void*)amm_all, dim3(NBLK), dim3(256), params, 0, stream);

    if (e != hipSuccess) {
        // Deterministic fallback: R13 two-dispatch path.
        amm_k1<<<dim3(769), 256, 0, stream>>>(x_q, x_z, c_q, c_s, c_z, x_s,
                                              lut_q, lut_s, lut_z,
                                              bias_q, bias_s, bias_z,
                                              idx8, lut8, biasf2);
        amm_phase2<<<dim3(N_ / 4), 256, 0, stream>>>(
            idx8, lut8, lut_s, biasf2, out_s, out_z, (int*)d_out);
    }
}

// Round 16
// 21.407 us; speedup vs baseline: 3.6206x; 3.6206x over previous
//
#include <hip/hip_runtime.h>
#include <math.h>

// Problem constants (fixed by the reference)
constexpr int B_    = 8;
constexpr int CIN_  = 128;
constexpr int COUT_ = 256;
constexpr int L_    = 784;
constexpr int N_    = B_ * L_;       // 6272
constexpr int NCB_  = 64;
constexpr int K_    = 16;
constexpr int SUB_  = 18;            // 2 channels x 9 taps

// ws layout (byte offsets). idx layout [cb][n] (cb-major).
constexpr size_t WS_IDX  = 0;                  // 64*6272 uchar = 401408 B
constexpr size_t WS_LUT8 = 0x100000;           // 262144 uchar = 256 KB
constexpr size_t WS_BF2  = 0x180000;           // 256 f32 (bias + folded consts)

// ---------------------------------------------------------------------------
// K1 (grid 512 = one co-resident wavefront): every block packs a 128-int4
// lut slice (tid<128) and runs the R9 argmin for (cb = bx&63, b = bx>>6);
// block 0 additionally preps bias. Logic validated in R15's phase A.
// ---------------------------------------------------------------------------
__global__ __launch_bounds__(256, 2) void amm_k1(
    const int* __restrict__ x_q, const int* __restrict__ x_z,
    const int* __restrict__ c_q, const float* __restrict__ c_s,
    const int* __restrict__ c_z, const float* __restrict__ x_s,
    const int* __restrict__ lut_q, const float* __restrict__ lut_s,
    const int* __restrict__ lut_z,
    const int* __restrict__ bias_q, const float* __restrict__ bias_s,
    const int* __restrict__ bias_z,
    unsigned char* __restrict__ idx8, unsigned char* __restrict__ lut8,
    float* __restrict__ biasf2)
{
    const int bx  = blockIdx.x;
    const int tid = threadIdx.x;

    __shared__ float sx[2][900];     // 30x30 zero-padded, 7.2 KB
    __shared__ float c_lds[288];     // [s][k] k-major, float(c_q - zc)
    __shared__ float y2_lds[16];

    // pack slice: 512 blocks x 128 int4 = all 262144 lut dwords
    if (tid < 128) {
        const int i = (bx * 128 + tid) * 4;
        const int4 v = *(const int4*)(lut_q + i);
        uchar4 o;
        o.x = (unsigned char)(v.x + 128);
        o.y = (unsigned char)(v.y + 128);
        o.z = (unsigned char)(v.z + 128);
        o.w = (unsigned char)(v.w + 128);
        *(uchar4*)(lut8 + i) = o;
    }
    if (bx == 0) {
        const double ls = (double)lut_s[0];
        const double c0 = (8192.0 + 64.0 * (double)lut_z[0]) * ls;
        biasf2[tid] = (float)((double)(bias_q[tid] - bias_z[0]) *
                              (double)bias_s[0] - c0);
    }

    const int cb = bx & 63;
    const int b  = bx >> 6;

    const int zc = c_z[cb];
    for (int i = tid; i < 1800; i += 256) ((float*)sx)[i] = 0.0f;
    for (int i = tid; i < 288; i += 256) {
        const int k = i / SUB_, s = i - k * SUB_;
        c_lds[s * 16 + k] = (float)(c_q[cb * 288 + i] - zc);   // exact int
    }
    __syncthreads();

    const int xz = x_z[0];
    for (int i = tid; i < 2 * 784; i += 256) {
        const int c2 = i >= 784;
        const int r  = i - c2 * 784;
        const int h  = r / 28;
        const int w  = r - h * 28;
        sx[c2][(h + 1) * 30 + (w + 1)] =
            (float)(x_q[(size_t)(b * CIN_ + 2 * cb + c2) * L_ + r] - xz);
    }
    if (tid < 16) {                 // y2 in double, same order as before
        const double csf = (double)c_s[cb];
        const double den = (double)x_s[0] * csf;
        double s2 = 0.0;
        for (int s = 0; s < SUB_; ++s) {
            const double d = (double)c_lds[s * 16 + tid] * csf;
            s2 += d * d;
        }
        y2_lds[tid] = (float)(int)rint(s2 / den);   // < 2^24 -> exact in f32
    }
    __syncthreads();

    if (tid < 196) {
        float tap[4][SUB_];
        int   posr[4];
        #pragma unroll
        for (int ps = 0; ps < 4; ++ps) {
            const int p  = tid + 196 * ps;
            posr[ps] = p;
            const int oh = p / 28;
            const int ow = p - oh * 28;
            const int base = oh * 30 + ow;
            #pragma unroll
            for (int c2 = 0; c2 < 2; ++c2)
                #pragma unroll
                for (int kh = 0; kh < 3; ++kh)
                    #pragma unroll
                    for (int kw = 0; kw < 3; ++kw)
                        tap[ps][c2 * 9 + kh * 3 + kw] =
                            sx[c2][base + kh * 30 + kw];
        }

        float bestd[4] = {3.0e38f, 3.0e38f, 3.0e38f, 3.0e38f};
        int   bestk[4] = {0, 0, 0, 0};

        #pragma unroll
        for (int kc = 0; kc < 4; ++kc) {
            float acc[4][4];
            #pragma unroll
            for (int ps = 0; ps < 4; ++ps)
                #pragma unroll
                for (int kk = 0; kk < 4; ++kk) acc[ps][kk] = 0.0f;

            #pragma unroll
            for (int s = 0; s < SUB_; ++s) {
                const float4 c4 = *(const float4*)&c_lds[s * 16 + kc * 4];
                #pragma unroll
                for (int ps = 0; ps < 4; ++ps) {
                    const float xs = tap[ps][s];
                    acc[ps][0] = fmaf(xs, c4.x, acc[ps][0]);
                    acc[ps][1] = fmaf(xs, c4.y, acc[ps][1]);
                    acc[ps][2] = fmaf(xs, c4.z, acc[ps][2]);
                    acc[ps][3] = fmaf(xs, c4.w, acc[ps][3]);
                }
            }
            #pragma unroll
            for (int kk = 0; kk < 4; ++kk) {
                const float yk = y2_lds[kc * 4 + kk];
                #pragma unroll
                for (int ps = 0; ps < 4; ++ps) {
                    const float d = fmaf(-2.0f, acc[ps][kk], yk);
                    if (d < bestd[ps]) { bestd[ps] = d; bestk[ps] = kc * 4 + kk; }
                }
            }
        }

        unsigned char* op = idx8 + (size_t)cb * N_ + b * L_;
        #pragma unroll
        for (int ps = 0; ps < 4; ++ps)
            op[posr[ps]] = (unsigned char)bestk[ps];
    }
}

// ---------------------------------------------------------------------------
// K2 (= R13 + XCD swizzle): wave = one position; dwordx4 gather (16 VMEM
// loads/wave); packed-u16 accumulation; shfl_xor merge; LDS transpose;
// int4 stores. Block swizzle g = (bid&7)*196 + (bid>>3) puts the 4 blocks
// that complete each 64-B output line on the SAME XCD so partial-line
// writes merge in that XCD's L2 instead of 4x HBM write amplification.
// ---------------------------------------------------------------------------
__global__ __launch_bounds__(256, 6) void amm_phase2(
    const unsigned char* __restrict__ idx8, const unsigned char* __restrict__ lut8,
    const float* __restrict__ lut_s, const float* __restrict__ biasf2,
    const float* __restrict__ out_s, const int* __restrict__ out_z,
    int* __restrict__ out)
{
    const int tid  = threadIdx.x;
    const int lane = tid & 63;
    const int wv   = __builtin_amdgcn_readfirstlane(tid >> 6);  // position
    const int bid  = blockIdx.x;
    const int g    = (bid & 7) * 196 + (bid >> 3);   // XCD-aware bijection
    const int nb   = g * 4;
    const int b    = nb / L_;          // uniform; 784%4==0 so no b crossing
    const int r0   = nb - b * L_;
    const int sh   = 8 * wv;

    __shared__ unsigned int sidx[64];      // [cb]: 4 pos bytes
    __shared__ unsigned int res[4][132];   // [pos][128 words = 256 couts] +pad

    if (tid < 64)
        sidx[tid] = *(const unsigned int*)(idx8 + (size_t)tid * N_ + nb);
    __syncthreads();

    const int cbq = lane >> 4;         // row class 0..3
    const int coq = lane & 15;         // 16B cout-quad within the row

    unsigned int acc[8] = {0, 0, 0, 0, 0, 0, 0, 0};
    #pragma unroll
    for (int tb = 0; tb < 4; ++tb) {   // 4 batches of 4 rounds (ILP)
        uint4 v[4];
        #pragma unroll
        for (int j = 0; j < 4; ++j) {
            const int cb = (tb * 4 + j) * 4 + cbq;
            const unsigned int k = (sidx[cb] >> sh) & 0xffu;
            v[j] = *(const uint4*)(lut8 + ((size_t)((cb << 4) + k) << 8)
                                        + (coq << 4));
        }
        #pragma unroll
        for (int j = 0; j < 4; ++j) {
            const unsigned int d[4] = {v[j].x, v[j].y, v[j].z, v[j].w};
            #pragma unroll
            for (int q = 0; q < 4; ++q) {
                acc[2 * q]     += d[q] & 0x00FF00FFu;
                acc[2 * q + 1] += (d[q] >> 8) & 0x00FF00FFu;
            }
        }
    }

    // merge the 4 row classes (u16 halves never overflow: <= 16320)
    #pragma unroll
    for (int j = 0; j < 8; ++j) {
        acc[j] += __shfl_xor(acc[j], 16, 64);
        acc[j] += __shfl_xor(acc[j], 32, 64);
    }
    if (cbq == 0) {
        #pragma unroll
        for (int j = 0; j < 8; ++j) res[wv][coq * 8 + j] = acc[j];
    }
    __syncthreads();

    // ---- epilogue: thread t owns cout = t; int4 store of 4 consecutive r ----
    const float lsf = lut_s[0];
    const float osf = out_s[0];
    const float ozf = (float)out_z[0];

    const int co   = tid;
    const int u    = (co >> 4) * 8 + ((co & 15) >> 2) * 2 + (co & 1);
    const int half = (co >> 1) & 1;
    const float bf = biasf2[co];

    int4 ov;
    int* ovp = (int*)&ov;
    #pragma unroll
    for (int p = 0; p < 4; ++p) {
        const unsigned int vv = res[p][u];
        const int sv = (int)((vv >> (16 * half)) & 0xffffu);
        float f = (float)sv * lsf + bf;
        f = fmaxf(f, 0.0f) / osf + ozf;
        f = fminf(fmaxf(f, -128.0f), 127.0f);
        ovp[p] = (int)rintf(f);
    }
    *(int4*)(out + (size_t)(b * COUT_ + co) * L_ + r0) = ov;
}

extern "C" void kernel_launch(void* const* d_in, const int* in_sizes, int n_in,
                              void* d_out, int out_size, void* d_ws, size_t ws_size,
                              hipStream_t stream)
{
    const int*   x_q    = (const int*)  d_in[0];
    const float* x_s    = (const float*)d_in[1];
    const int*   x_z    = (const int*)  d_in[2];
    const int*   c_q    = (const int*)  d_in[3];
    const float* c_s    = (const float*)d_in[4];
    const int*   c_z    = (const int*)  d_in[5];
    const int*   lut_q  = (const int*)  d_in[6];
    const float* lut_s  = (const float*)d_in[7];
    const int*   lut_z  = (const int*)  d_in[8];
    const int*   bias_q = (const int*)  d_in[9];
    const float* bias_s = (const float*)d_in[10];
    const int*   bias_z = (const int*)  d_in[11];
    const float* out_s  = (const float*)d_in[12];
    const int*   out_z  = (const int*)  d_in[13];

    char* ws = (char*)d_ws;
    unsigned char* idx8 = (unsigned char*)(ws + WS_IDX);
    unsigned char* lut8 = (unsigned char*)(ws + WS_LUT8);
    float* biasf2 = (float*)(ws + WS_BF2);

    amm_k1<<<dim3(512), 256, 0, stream>>>(x_q, x_z, c_q, c_s, c_z, x_s,
                                          lut_q, lut_s, lut_z,
                                          bias_q, bias_s, bias_z,
                                          idx8, lut8, biasf2);

    amm_phase2<<<dim3(N_ / 4), 256, 0, stream>>>(
        idx8, lut8, lut_s, biasf2, out_s, out_z, (int*)d_out);
}